// Round 16
// baseline (160.595 us; speedup 1.0000x reference)
//
#include <hip/hip_runtime.h>
#include <math.h>

#define SHEET 160
#define LTOT (SHEET*SHEET)          // 25600
#define F_AFF 450
#define F_LAT 625
#define N_ITERS 10
#define IN_HW 174                   // SHEET + AFF_K - 1
#define HOMEO 0.02f
#define PI_D 3.14159265358979323846

typedef float    f32x4 __attribute__((ext_vector_type(4)));
typedef unsigned u32x4 __attribute__((ext_vector_type(4)));

// ---- k_lat tile geometry: 10 rows x 5 cols of locations, 2 blocks/CU ----
#define BH 10
#define BW 5
#define BLK 320                     // 5 waves; wave w owns rows i0+2w, i0+2w+1
#define TCOLS (SHEET/BW)            // 32
#define GRID_L ((SHEET/BH)*TCOLS)   // 16*32 = 512 blocks = exactly 2/CU
#define EH 58                       // BH + 48 E-field rows
#define EWH 28                      // 27 data parity cols + pad
#define EP_HALF (EH*EWH)            // 1624
#define EP_N (2*EP_HALF)            // 3248
#define LW 64                       // 57 data cols padded to 64 (shift addressing)
#define LH 62                       // BH + 52
#define LT_N (LH*LW)                // 3968

// ---- k_hebb tile geometry: 10 x 10, 1 block/CU (r14-proven) ----
#define HBH 10
#define HBW 10
#define HBLK 640
#define HTCOLS (SHEET/HBW)          // 16
#define HGRID ((SHEET/HBH)*HTCOLS)  // 256
#define HEWH 30
#define HEP_HALF (58*HEWH)          // 1740
#define HEP_N (2*HEP_HALF)          // 3480

// pre-pass geometry: 256-thread blocks, 8 rows each, role-split grid
#define PBLK 256
#define RPB 8
#define NABLK (LTOT/RPB)            // 3200 blocks per role

#define NPAIR 256                   // packed words per location (4 per lane, nz-compacted)

// ---- workspace layout (float offsets) ----
#define WS_SRE    0                 // 32 (25 used)
#define WS_PKF    32                // int[512]   pack-order f index
#define WS_PKL    544               // float[512] pack-order lri
#define WS_OFFT   1056              // int[512]   gather offset for k_lat  (stride 2*EWH)
#define WS_OFF2   1568              // int[512]   gather offset for k_hebb (stride 2*HEWH)
#define WS_AFFTAB 2080              // float2[512] {env, off}
#define WS_AFF    3104
#define WS_B0     (WS_AFF + LTOT)
#define WS_B1     (WS_B0  + LTOT)
#define WS_LM     (WS_B1  + LTOT)
#define WS_WQ     (WS_LM  + LTOT + 64)   // 25600*256 u32 = 26.2 MB

// DPP wave-64 sum: result lands in lane 63 (VALU pipe, no LDS traffic)
__device__ __forceinline__ float wred_dpp(float v) {
    v += __int_as_float(__builtin_amdgcn_update_dpp(0, __float_as_int(v), 0x111, 0xf, 0xf, true)); // row_shr:1
    v += __int_as_float(__builtin_amdgcn_update_dpp(0, __float_as_int(v), 0x112, 0xf, 0xf, true)); // row_shr:2
    v += __int_as_float(__builtin_amdgcn_update_dpp(0, __float_as_int(v), 0x114, 0xf, 0xf, true)); // row_shr:4
    v += __int_as_float(__builtin_amdgcn_update_dpp(0, __float_as_int(v), 0x118, 0xf, 0xf, true)); // row_shr:8
    v += __int_as_float(__builtin_amdgcn_update_dpp(0, __float_as_int(v), 0x142, 0xa, 0xf, true)); // bcast15
    v += __int_as_float(__builtin_amdgcn_update_dpp(0, __float_as_int(v), 0x143, 0xc, 0xf, true)); // bcast31
    return v;
}

__device__ __forceinline__ unsigned f2bf(float f) {   // RNE float->bf16 bits
    unsigned u = __float_as_uint(f);
    return (u + 0x7FFFu + ((u >> 16) & 1u)) >> 16;
}
__device__ __forceinline__ float bflo(unsigned p) { return __uint_as_float(p << 16); }
__device__ __forceinline__ float bfhi(unsigned p) { return __uint_as_float(p & 0xffff0000u); }

// ---------------- init: constant tables + nz-compacted pack tables + scalar zero ----------------
__global__ __launch_bounds__(1024) void k_init(float* __restrict__ ws,
                                               float* __restrict__ out) {
    __shared__ float red[1024];
    __shared__ float lriS[640];
    __shared__ int   nzf[512];
    __shared__ int   wcnt[16];
    const int t = threadIdx.x;
    const int lane = t & 63, wvi = t >> 6;

    if (t == 0) out[2 * LTOT] = 0.f;   // k_hebb atomicAdds into this

    float sre_raw = 0.f;
    if (t < 25) {
        int u = t / 5, v = t % 5;
        double d = sqrt((double)((u-2)*(u-2) + (v-2)*(v-2)));
        if (d < 2.5) { double cv = cos(fmin(d/5.0, 1.0) * PI_D * 0.5); sre_raw = (float)(cv*cv); }
    }

    float lri_raw = 0.f;
    const int dy = t / 25, dx = t % 25;
    if (t < 625) {
        double d = sqrt((double)((dy-12)*(dy-12) + (dx-12)*(dx-12)));
        double base = 0.0, inh = 0.0;
        if (d < 12.5) { double cv = cos(fmin(d/25.0, 1.0) * PI_D * 0.5); base = cv*cv; }
        if (d < 1.25) { double cv = cos(fmin(d/2.5,  1.0) * PI_D * 0.5); inh  = cv*cv; }
        lri_raw = (float)(base * (1.0 - inh));
    }
    const bool nz = (lri_raw != 0.f);
    if (t < 640) lriS[t] = lri_raw;

    red[t] = lri_raw;
    __syncthreads();
    #pragma unroll
    for (int s = 512; s > 0; s >>= 1) {
        if (t < s) red[t] = fmaxf(red[t], red[t + s]);
        __syncthreads();
    }
    const float lri_max = red[0];
    __syncthreads();

    red[t] = sre_raw;
    __syncthreads();
    #pragma unroll
    for (int s = 512; s > 0; s >>= 1) {
        if (t < s) red[t] += red[t + s];
        __syncthreads();
    }
    const float sre_sum = red[0];

    if (t < 32) ws[WS_SRE + t] = (t < 25) ? sre_raw / sre_sum : 0.f;

    // ---- ballot prefix-scan -> compacted nonzero-lri list (488 entries) ----
    unsigned long long bal = __ballot(nz);
    if (lane == 0) wcnt[wvi] = __popcll(bal);
    __syncthreads();
    int woff = 0, ntot = 0;
    #pragma unroll
    for (int v2 = 0; v2 < 16; ++v2) { int c = wcnt[v2]; if (v2 < wvi) woff += c; ntot += c; }
    if (nz) nzf[woff + __popcll(bal & ((1ull << lane) - 1ull))] = t;
    __syncthreads();

    // pack tables: slot (2q+h)*64+lane <- nzf[2*(q*64+lane)+h]
    if (t < 256) {
        #pragma unroll
        for (int h = 0; h < 2; ++h) {
            int idx = 2*t + h;
            int f = 624, off1 = 0, off2 = 0; float lv = 0.f;
            if (idx < ntot) {
                f = nzf[idx];
                int fy = f / 25, fx = f - 25*fy;
                off1 = fy * (2*EWH)  + fx;     // k_lat parity-half stride
                off2 = fy * (2*HEWH) + fx;     // k_hebb parity-half stride
                lv = lriS[f] / lri_max;
            }
            int slot = (2*(t >> 6) + h)*64 + (t & 63);
            ((int*)  (ws + WS_PKF ))[slot] = f;
            ((float*)(ws + WS_PKL ))[slot] = lv;
            ((int*)  (ws + WS_OFFT))[slot] = off1;
            ((int*)  (ws + WS_OFF2))[slot] = off2;
        }
    }

    // afferent table: {env, x offset}
    if (t < 512) {
        float ev = 0.f; int off = 0;
        if (t < 450) {
            int c  = t / 225, rr = t % 225;
            int kh = rr / 15, kw = rr % 15;
            double d = sqrt((double)((kh-7)*(kh-7) + (kw-7)*(kw-7)));
            if (d < 7.5) { double cv = cos(fmin(d/15.0, 1.0) * PI_D * 0.5); ev = (float)(cv*cv); }
            off = c * (IN_HW*IN_HW) + kh * IN_HW + kw;
        }
        ((float2*)(ws + WS_AFFTAB))[t] = make_float2(ev, __int_as_float(off));
    }
}

// ---------------- pre-pass: float4-staged streaming, 20KB LDS -> 8 blocks/CU ----------------
// blocks [0, NABLK): afferent (rfs).  blocks [NABLK, 2*NABLK): latw pack.
__global__ __launch_bounds__(PBLK, 8) void k_pre(const float* __restrict__ x,
                                                 const float* __restrict__ rfs,
                                                 const float* __restrict__ latw,
                                                 const float* __restrict__ ada,
                                                 float* __restrict__ out_rawaff,
                                                 float* __restrict__ ws,
                                                 unsigned* __restrict__ wq) {
    __shared__ __align__(16) float S[5008];    // 20 KB: pack 5000, aff 3600
    const int tid = threadIdx.x;
    const int w = tid >> 6, lane = tid & 63;

    if (blockIdx.x < NABLK) {
        // ---- afferent role: stage 8 rows of rfs (900 float4, 4 indep loads/thread) ----
        const int l0 = blockIdx.x * RPB;
        const f32x4* src4 = (const f32x4*)(rfs + (size_t)l0 * F_AFF);
        #pragma unroll
        for (int k = 0; k < 4; ++k) {
            int idx = k * PBLK + tid;
            if (idx < 900) ((f32x4*)S)[idx] = __builtin_nontemporal_load(src4 + idx);
        }

        // hoist afferent table into regs (shared across the wave's 2 rows)
        float envA[8]; int offA[8];
        const float2* atab = (const float2*)(ws + WS_AFFTAB);
        #pragma unroll
        for (int it = 0; it < 8; ++it) {
            float2 tb = atab[it*64 + lane];
            envA[it] = tb.x; offA[it] = __float_as_int(tb.y);
        }
        __syncthreads();

        #pragma unroll
        for (int s = 0; s < 2; ++s) {
            const int row = 2*w + s, l = l0 + row;
            const int i = l / SHEET, j = l % SHEET;
            const int xbase = i * IN_HW + j;
            const float* Srow = S + row * F_AFF;
            float dot = 0.f, rs = 0.f;
            #pragma unroll
            for (int it = 0; it < 8; ++it) {
                int f = it*64 + lane;
                float r = (f < F_AFF) ? Srow[f] : 0.f;
                float xv = x[xbase + offA[it]];
                dot = fmaf(xv * envA[it], r, dot);
                rs += r;
            }
            dot = wred_dpp(dot); rs = wred_dpp(rs);
            if (lane == 63) {
                float a = dot / rs;
                out_rawaff[l] = 45.0f * a;             // raw_aff
                float aff = a - ada[l];
                ws[WS_AFF + l] = aff;
                ws[WS_B0  + l] = fmaxf(aff, 0.f);      // lat_0 = relu(aff)
                ws[WS_LM  + l] = 0.f;
            }
        }
    } else {
        // ---- pack role: stage 8 rows of latw (1250 float4, 5 indep loads/thread) ----
        const int l0 = (blockIdx.x - NABLK) * RPB;
        const f32x4* src4 = (const f32x4*)(latw + (size_t)l0 * F_LAT);
        #pragma unroll
        for (int k = 0; k < 5; ++k) {
            int idx = k * PBLK + tid;
            if (idx < 1250) ((f32x4*)S)[idx] = __builtin_nontemporal_load(src4 + idx);
        }

        // hoist pack tables into regs
        int pf[8]; float pl[8];
        #pragma unroll
        for (int q8 = 0; q8 < 8; ++q8) {
            pf[q8] = ((const int*)  (ws + WS_PKF))[q8*64 + lane];
            pl[q8] = ((const float*)(ws + WS_PKL))[q8*64 + lane];
        }
        __syncthreads();

        #pragma unroll
        for (int s = 0; s < 2; ++s) {
            const int row = 2*w + s, l = l0 + row;
            const float* Srow = S + row * F_LAT;
            float sum = 0.f;
            #pragma unroll
            for (int it = 0; it < 10; ++it) {
                int f = it*64 + lane;
                sum += (f < F_LAT) ? Srow[f] : 0.f;
            }
            sum = wred_dpp(sum);
            const float inv = 1.0f / __int_as_float(__builtin_amdgcn_readlane(__float_as_int(sum), 63));
            // per-lane-contiguous layout: one coalesced 16B store per lane
            u32x4 pk;
            #pragma unroll
            for (int q = 0; q < 4; ++q) {
                unsigned lo = f2bf(Srow[pf[2*q]]     * pl[2*q]     * inv);
                unsigned hi = f2bf(Srow[pf[2*q + 1]] * pl[2*q + 1] * inv);
                pk[q] = lo | (hi << 16);
            }
            *(u32x4*)(wq + (size_t)l * NPAIR + (lane << 2)) = pk;
        }
    }
}

// ---------------- lateral iteration: 10x5 tile, 2 blocks/CU (phase overlap) ----------------
__global__ __launch_bounds__(BLK, 2) void k_lat(const unsigned* __restrict__ wq,
                                                float* __restrict__ ws,
                                                const float* __restrict__ lsrc,
                                                float* __restrict__ lat_out) {
    __shared__ __align__(16) float Lt[LT_N];
    __shared__ __align__(16) float Ep[EP_N];
    const int b  = blockIdx.x;
    const int i0 = (b / TCOLS) * BH;
    const int j0 = (b % TCOLS) * BW;
    const int tid = threadIdx.x;
    const int w = tid >> 6, lane = tid & 63;
    // wave w owns rows i0+2w, i0+2w+1, cols j0..j0+4 ; s = r*5+c

    // per-lane gather offsets (8 compacted slots, parity-half stride 2*EWH)
    const int* offT = (const int*)(ws + WS_OFFT);
    int offr[8];
    #pragma unroll
    for (int q8 = 0; q8 < 8; ++q8) offr[q8] = offT[q8*64 + lane];

    // prefetch 10 locations' packed weights: one b128 per location
    u32x4 wp[10];
    #pragma unroll
    for (int s = 0; s < 10; ++s) {
        int r = s / 5, c = s - 5 * r;
        wp[s] = *(const u32x4*)(wq + (size_t)((i0 + 2*w + r) * SHEET + j0 + c) * NPAIR + (lane << 2));
    }
    __builtin_amdgcn_sched_barrier(0);

    // sre (uniform -> scalar loads)
    float sreg[25];
    #pragma unroll
    for (int q = 0; q < 25; ++q) sreg[q] = ws[WS_SRE + q];

    // ---- stage L tile (pad = HOMEO), 62 rows x 57 cols in [62][64] ----
    for (int idx = tid; idx < LT_N; idx += BLK) {
        int r = idx >> 6, c = idx & 63;
        int y  = i0 + r - 26;
        int xx = j0 + c - 26;
        float v = HOMEO;
        if (c < 57 && (unsigned)y < SHEET && (unsigned)xx < SHEET) v = lsrc[y*SHEET + xx];
        Lt[idx] = v;
    }
    __syncthreads();

    // ---- 5x5 conv -> E field 58x53, parity-split store (14 quads/row) ----
    for (int qi = tid; qi < EH * 14; qi += BLK) {
        int y = qi / 14, q = qi - y * 14;
        int x0 = q * 4;
        float a0 = 0.f, a1 = 0.f, a2 = 0.f, a3 = 0.f;
        #pragma unroll
        for (int u = 0; u < 5; ++u) {
            const float* row = &Lt[(y + u) * LW + x0];
            float ra[8];
            #pragma unroll
            for (int v = 0; v < 8; ++v) ra[v] = row[v];
            #pragma unroll
            for (int v = 0; v < 5; ++v) {
                float s = sreg[u * 5 + v];
                a0 = fmaf(ra[v],     s, a0);
                a1 = fmaf(ra[v + 1], s, a1);
                a2 = fmaf(ra[v + 2], s, a2);
                a3 = fmaf(ra[v + 3], s, a3);
            }
        }
        int yg = i0 - 24 + y;
        bool yok = (unsigned)yg < SHEET;
        int xg = j0 - 24 + x0;
        float v0 = (yok && (unsigned)(xg    ) < SHEET) ? a0 : HOMEO;
        float v1 = (yok && (unsigned)(xg + 1) < SHEET) ? a1 : HOMEO;
        float v2 = (yok && (unsigned)(xg + 2) < SHEET) ? a2 : HOMEO;
        float v3 = (yok && (unsigned)(xg + 3) < SHEET) ? a3 : HOMEO;
        int c0 = y * EWH + 2 * q;
        Ep[c0]               = v0;   // q=13 writes land in the per-row pad slot
        Ep[EP_HALF + c0]     = v1;   // (idx 26/27 odd-half) - never gathered
        Ep[c0 + 1]           = v2;
        Ep[EP_HALF + c0 + 1] = v3;
    }
    __syncthreads();

    // ---- per-location 625-dot from register-resident bf16 weights ----
    float acc[10];
    #pragma unroll
    for (int s = 0; s < 10; ++s) {
        int r = s / 5, c = s - 5 * r;
        const int gbase = (c & 1) * EP_HALF + (2*w + r) * EWH + (c >> 1);
        float a = 0.f;
        #pragma unroll
        for (int k = 0; k < 4; ++k) {
            unsigned p = wp[s][k];
            float e0 = Ep[gbase + offr[2*k]];
            float e1 = Ep[gbase + offr[2*k + 1]];
            a = fmaf(e0, bflo(p), a);
            a = fmaf(e1, bfhi(p), a);
        }
        acc[s] = a;
    }
    #pragma unroll
    for (int s = 0; s < 10; ++s) acc[s] = wred_dpp(acc[s]);

    // broadcast acc[s] to lane s; lanes 0-9 finish their locations in parallel
    float accs = 0.f;
    #pragma unroll
    for (int s = 0; s < 10; ++s) {
        float a = __int_as_float(__builtin_amdgcn_readlane(__float_as_int(acc[s]), 63));
        if (lane == s) accs = a;
    }
    if (lane < 10) {
        int r = (lane >= 5) ? 1 : 0;
        int c = lane - 5 * r;
        int l = (i0 + 2*w + r) * SHEET + j0 + c;
        float ec = Ep[(c & 1) * EP_HALF + (2*w + r + 24) * EWH + (c >> 1) + 12];
        float v = ec * 0.45f - accs * 0.55f + ws[WS_AFF + l];
        v = tanhf(fmaxf(v, 0.f));
        lat_out[l] = v;
        ws[WS_LM + l] += v;
    }
}

// ---------------- hebbian correlation: 10x10 tiling, 1 block/CU, atomic sum ----------------
__global__ __launch_bounds__(HBLK, 3) void k_hebb(const unsigned* __restrict__ wq,
                                                  float* __restrict__ ws,
                                                  float* __restrict__ out_scalar) {
    __shared__ float LMp[HEP_N];
    __shared__ float part[10];
    const int b  = blockIdx.x;
    const int i0 = (b / HTCOLS) * HBH;
    const int j0 = (b % HTCOLS) * HBW;
    const int tid = threadIdx.x;
    const int w = tid >> 6, lane = tid & 63;
    const int lrow = (i0 + w) * SHEET + j0;
    const float* lm = ws + WS_LM;

    const int* offT = (const int*)(ws + WS_OFF2);
    int offr[8];
    #pragma unroll
    for (int q8 = 0; q8 < 8; ++q8) offr[q8] = offT[q8*64 + lane];

    u32x4 wp[10];
    #pragma unroll
    for (int s = 0; s < 10; ++s)
        wp[s] = *(const u32x4*)(wq + (size_t)(lrow + s) * NPAIR + (lane << 2));
    __builtin_amdgcn_sched_barrier(0);

    // stage lat_mean tile (x0.1, pad HOMEO), parity-split 58x58
    for (int idx = tid; idx < HEP_N; idx += HBLK) {
        int p   = idx / HEP_HALF;
        int rem = idx - p * HEP_HALF;
        int y   = rem / HEWH;
        int col = rem - y * HEWH;
        int yg = i0 - 24 + y;
        int xg = j0 - 24 + 2 * col + p;
        float v = HOMEO;
        if ((unsigned)yg < SHEET && (unsigned)xg < SHEET && col < 29) v = lm[yg*SHEET + xg] * 0.1f;
        LMp[idx] = v;
    }
    __syncthreads();

    float acc[10];
    #pragma unroll
    for (int s = 0; s < 10; ++s) {
        const int gbase = (s & 1) * HEP_HALF + w * HEWH + (s >> 1);
        float a = 0.f;
        #pragma unroll
        for (int k = 0; k < 4; ++k) {
            unsigned p = wp[s][k];
            float e0 = LMp[gbase + offr[2*k]];
            float e1 = LMp[gbase + offr[2*k + 1]];
            a = fmaf(e0, bflo(p), a);
            a = fmaf(e1, bfhi(p), a);
        }
        acc[s] = a;
    }
    #pragma unroll
    for (int s = 0; s < 10; ++s) acc[s] = wred_dpp(acc[s]);

    if (lane == 63) {
        float wacc = 0.f;
        #pragma unroll
        for (int s = 0; s < 10; ++s) {
            float lmv = LMp[(s & 1) * HEP_HALF + (w + 24) * HEWH + (s >> 1) + 12];
            wacc += lmv * 62.5f * acc[s];
        }
        part[w] = wacc;
    }
    __syncthreads();
    if (tid == 0) {
        float s = 0.f;
        #pragma unroll
        for (int q = 0; q < 10; ++q) s += part[q];
        atomicAdd(out_scalar, s);
    }
}

extern "C" void kernel_launch(void* const* d_in, const int* in_sizes, int n_in,
                              void* d_out, int out_size, void* d_ws, size_t ws_size,
                              hipStream_t stream) {
    const float* x    = (const float*)d_in[0];
    const float* rfs  = (const float*)d_in[1];
    const float* latw = (const float*)d_in[2];
    const float* ada  = (const float*)d_in[3];
    float* out = (float*)d_out;
    float* ws  = (float*)d_ws;
    unsigned* wq = (unsigned*)(ws + WS_WQ);

    k_init<<<1, 1024, 0, stream>>>(ws, out);
    k_pre<<<2 * NABLK, PBLK, 0, stream>>>(x, rfs, latw, ada, out, ws, wq);

    for (int t = 0; t < N_ITERS; ++t) {
        const float* src = ws + ((t & 1) ? WS_B1 : WS_B0);
        float* dst = (t == N_ITERS - 1) ? (out + LTOT)
                                        : (ws + ((t & 1) ? WS_B0 : WS_B1));
        k_lat<<<GRID_L, BLK, 0, stream>>>(wq, ws, src, dst);
    }

    k_hebb<<<HGRID, HBLK, 0, stream>>>(wq, ws, out + 2 * LTOT);
}

// Round 17
// 135.355 us; speedup vs baseline: 1.1865x; 1.1865x over previous
//
#include <hip/hip_runtime.h>
#include <math.h>

#define SHEET 160
#define LTOT (SHEET*SHEET)          // 25600
#define F_AFF 450
#define F_LAT 625
#define N_ITERS 10
#define IN_HW 174                   // SHEET + AFF_K - 1
#define HOMEO 0.02f
#define PI_D 3.14159265358979323846

typedef float    f32x4 __attribute__((ext_vector_type(4)));
typedef unsigned u32x4 __attribute__((ext_vector_type(4)));

// ---- lateral tile geometry: 10 x 10 locations per block, 1 block/CU ----
#define BH 10
#define BW 10
#define BLK 640                     // 10 waves, each owns one row (10 locations)
#define TCOLS (SHEET/BW)            // 16
#define GRID_L ((SHEET/BH)*TCOLS)   // 256 blocks = exactly 1/CU
#define EH 58                       // BH + 48 E-field rows
#define EWH 30                      // 29 data cols per parity half + 1 pad
#define EP_HALF (EH*EWH)            // 1740
#define EP_N (2*EP_HALF)            // 3480
#define LW 64                       // 62 data cols padded to 64
#define LH 62                       // BH + 52
#define LT_N (LH*LW)                // 3968

// pre-pass geometry: 256-thread blocks, 8 rows each, role-split grid
#define PBLK 256
#define RPB 8
#define NABLK (LTOT/RPB)            // 3200 blocks per role

#define NPAIR 256                   // packed words per location (4 per lane, nz-compacted)

// ---- workspace layout (float offsets) ----
#define WS_SRE    0                 // 32 (25 used)
#define WS_PKF    32                // int[512]   pack-order f index
#define WS_PKL    544               // float[512] pack-order lri
#define WS_OFFT   1056              // int[512]   pack-order gather offset (parity-half stride)
#define WS_AFFTAB 1568              // float2[512] {env, off}
#define WS_AFF    2592
#define WS_B0     (WS_AFF + LTOT)
#define WS_B1     (WS_B0  + LTOT)
#define WS_LM     (WS_B1  + LTOT)
#define WS_WQ     (WS_LM  + LTOT + 64)   // 25600*256 u32 = 26.2 MB

// DPP wave-64 sum: result lands in lane 63 (VALU pipe, no LDS traffic)
__device__ __forceinline__ float wred_dpp(float v) {
    v += __int_as_float(__builtin_amdgcn_update_dpp(0, __float_as_int(v), 0x111, 0xf, 0xf, true)); // row_shr:1
    v += __int_as_float(__builtin_amdgcn_update_dpp(0, __float_as_int(v), 0x112, 0xf, 0xf, true)); // row_shr:2
    v += __int_as_float(__builtin_amdgcn_update_dpp(0, __float_as_int(v), 0x114, 0xf, 0xf, true)); // row_shr:4
    v += __int_as_float(__builtin_amdgcn_update_dpp(0, __float_as_int(v), 0x118, 0xf, 0xf, true)); // row_shr:8
    v += __int_as_float(__builtin_amdgcn_update_dpp(0, __float_as_int(v), 0x142, 0xa, 0xf, true)); // bcast15
    v += __int_as_float(__builtin_amdgcn_update_dpp(0, __float_as_int(v), 0x143, 0xc, 0xf, true)); // bcast31
    return v;
}

__device__ __forceinline__ unsigned f2bf(float f) {   // RNE float->bf16 bits
    unsigned u = __float_as_uint(f);
    return (u + 0x7FFFu + ((u >> 16) & 1u)) >> 16;
}
__device__ __forceinline__ float bflo(unsigned p) { return __uint_as_float(p << 16); }
__device__ __forceinline__ float bfhi(unsigned p) { return __uint_as_float(p & 0xffff0000u); }

// ---------------- init: constant tables + nz-compacted pack tables + scalar zero ----------------
__global__ __launch_bounds__(1024) void k_init(float* __restrict__ ws,
                                               float* __restrict__ out) {
    __shared__ float red[1024];
    __shared__ float lriS[640];
    __shared__ int   nzf[512];
    __shared__ int   wcnt[16];
    const int t = threadIdx.x;
    const int lane = t & 63, wvi = t >> 6;

    if (t == 0) out[2 * LTOT] = 0.f;   // k_hebb atomicAdds into this

    float sre_raw = 0.f;
    if (t < 25) {
        int u = t / 5, v = t % 5;
        double d = sqrt((double)((u-2)*(u-2) + (v-2)*(v-2)));
        if (d < 2.5) { double cv = cos(fmin(d/5.0, 1.0) * PI_D * 0.5); sre_raw = (float)(cv*cv); }
    }

    float lri_raw = 0.f;
    const int dy = t / 25, dx = t % 25;
    if (t < 625) {
        double d = sqrt((double)((dy-12)*(dy-12) + (dx-12)*(dx-12)));
        double base = 0.0, inh = 0.0;
        if (d < 12.5) { double cv = cos(fmin(d/25.0, 1.0) * PI_D * 0.5); base = cv*cv; }
        if (d < 1.25) { double cv = cos(fmin(d/2.5,  1.0) * PI_D * 0.5); inh  = cv*cv; }
        lri_raw = (float)(base * (1.0 - inh));
    }
    const bool nz = (lri_raw != 0.f);
    if (t < 640) lriS[t] = lri_raw;

    red[t] = lri_raw;
    __syncthreads();
    #pragma unroll
    for (int s = 512; s > 0; s >>= 1) {
        if (t < s) red[t] = fmaxf(red[t], red[t + s]);
        __syncthreads();
    }
    const float lri_max = red[0];
    __syncthreads();

    red[t] = sre_raw;
    __syncthreads();
    #pragma unroll
    for (int s = 512; s > 0; s >>= 1) {
        if (t < s) red[t] += red[t + s];
        __syncthreads();
    }
    const float sre_sum = red[0];

    if (t < 32) ws[WS_SRE + t] = (t < 25) ? sre_raw / sre_sum : 0.f;

    // ---- ballot prefix-scan -> compacted nonzero-lri list (488 entries) ----
    unsigned long long bal = __ballot(nz);
    if (lane == 0) wcnt[wvi] = __popcll(bal);
    __syncthreads();
    int woff = 0, ntot = 0;
    #pragma unroll
    for (int v2 = 0; v2 < 16; ++v2) { int c = wcnt[v2]; if (v2 < wvi) woff += c; ntot += c; }
    if (nz) nzf[woff + __popcll(bal & ((1ull << lane) - 1ull))] = t;
    __syncthreads();

    // pack tables: slot (2q+h)*64+lane <- nzf[2*(q*64+lane)+h]
    if (t < 256) {
        #pragma unroll
        for (int h = 0; h < 2; ++h) {
            int idx = 2*t + h;
            int f = 624, off = 0; float lv = 0.f;
            if (idx < ntot) {
                f = nzf[idx];
                int fy = f / 25, fx = f - 25*fy;
                off = fy * (2*EWH) + fx;
                lv = lriS[f] / lri_max;
            }
            int slot = (2*(t >> 6) + h)*64 + (t & 63);
            ((int*)  (ws + WS_PKF ))[slot] = f;
            ((float*)(ws + WS_PKL ))[slot] = lv;
            ((int*)  (ws + WS_OFFT))[slot] = off;
        }
    }

    // afferent table: {env, x offset}
    if (t < 512) {
        float ev = 0.f; int off = 0;
        if (t < 450) {
            int c  = t / 225, rr = t % 225;
            int kh = rr / 15, kw = rr % 15;
            double d = sqrt((double)((kh-7)*(kh-7) + (kw-7)*(kw-7)));
            if (d < 7.5) { double cv = cos(fmin(d/15.0, 1.0) * PI_D * 0.5); ev = (float)(cv*cv); }
            off = c * (IN_HW*IN_HW) + kh * IN_HW + kw;
        }
        ((float2*)(ws + WS_AFFTAB))[t] = make_float2(ev, __int_as_float(off));
    }
}

// ---------------- pre-pass: float4-staged streaming, 20KB LDS -> 8 blocks/CU ----------------
// blocks [0, NABLK): afferent (rfs).  blocks [NABLK, 2*NABLK): latw pack.
__global__ __launch_bounds__(PBLK, 8) void k_pre(const float* __restrict__ x,
                                                 const float* __restrict__ rfs,
                                                 const float* __restrict__ latw,
                                                 const float* __restrict__ ada,
                                                 float* __restrict__ out_rawaff,
                                                 float* __restrict__ ws,
                                                 unsigned* __restrict__ wq) {
    __shared__ __align__(16) float S[5008];    // 20 KB: pack 5000, aff 3600
    const int tid = threadIdx.x;
    const int w = tid >> 6, lane = tid & 63;

    if (blockIdx.x < NABLK) {
        // ---- afferent role: stage 8 rows of rfs (900 float4, 4 indep loads/thread) ----
        const int l0 = blockIdx.x * RPB;
        const f32x4* src4 = (const f32x4*)(rfs + (size_t)l0 * F_AFF);
        #pragma unroll
        for (int k = 0; k < 4; ++k) {
            int idx = k * PBLK + tid;
            if (idx < 900) ((f32x4*)S)[idx] = __builtin_nontemporal_load(src4 + idx);
        }

        // hoist afferent table into regs (shared across the wave's 2 rows)
        float envA[8]; int offA[8];
        const float2* atab = (const float2*)(ws + WS_AFFTAB);
        #pragma unroll
        for (int it = 0; it < 8; ++it) {
            float2 tb = atab[it*64 + lane];
            envA[it] = tb.x; offA[it] = __float_as_int(tb.y);
        }
        __syncthreads();

        #pragma unroll
        for (int s = 0; s < 2; ++s) {
            const int row = 2*w + s, l = l0 + row;
            const int i = l / SHEET, j = l % SHEET;
            const int xbase = i * IN_HW + j;
            const float* Srow = S + row * F_AFF;
            float dot = 0.f, rs = 0.f;
            #pragma unroll
            for (int it = 0; it < 8; ++it) {
                int f = it*64 + lane;
                float r = (f < F_AFF) ? Srow[f] : 0.f;
                float xv = x[xbase + offA[it]];
                dot = fmaf(xv * envA[it], r, dot);
                rs += r;
            }
            dot = wred_dpp(dot); rs = wred_dpp(rs);
            if (lane == 63) {
                float a = dot / rs;
                out_rawaff[l] = 45.0f * a;             // raw_aff
                float aff = a - ada[l];
                ws[WS_AFF + l] = aff;
                ws[WS_B0  + l] = fmaxf(aff, 0.f);      // lat_0 = relu(aff)
                ws[WS_LM  + l] = 0.f;
            }
        }
    } else {
        // ---- pack role: stage 8 rows of latw (1250 float4, 5 indep loads/thread) ----
        const int l0 = (blockIdx.x - NABLK) * RPB;
        const f32x4* src4 = (const f32x4*)(latw + (size_t)l0 * F_LAT);
        #pragma unroll
        for (int k = 0; k < 5; ++k) {
            int idx = k * PBLK + tid;
            if (idx < 1250) ((f32x4*)S)[idx] = __builtin_nontemporal_load(src4 + idx);
        }

        // hoist pack tables into regs
        int pf[8]; float pl[8];
        #pragma unroll
        for (int q8 = 0; q8 < 8; ++q8) {
            pf[q8] = ((const int*)  (ws + WS_PKF))[q8*64 + lane];
            pl[q8] = ((const float*)(ws + WS_PKL))[q8*64 + lane];
        }
        __syncthreads();

        #pragma unroll
        for (int s = 0; s < 2; ++s) {
            const int row = 2*w + s, l = l0 + row;
            const float* Srow = S + row * F_LAT;
            float sum = 0.f;
            #pragma unroll
            for (int it = 0; it < 10; ++it) {
                int f = it*64 + lane;
                sum += (f < F_LAT) ? Srow[f] : 0.f;
            }
            sum = wred_dpp(sum);
            const float inv = 1.0f / __int_as_float(__builtin_amdgcn_readlane(__float_as_int(sum), 63));
            // per-lane-contiguous layout: one coalesced 16B store per lane
            u32x4 pk;
            #pragma unroll
            for (int q = 0; q < 4; ++q) {
                unsigned lo = f2bf(Srow[pf[2*q]]     * pl[2*q]     * inv);
                unsigned hi = f2bf(Srow[pf[2*q + 1]] * pl[2*q + 1] * inv);
                pk[q] = lo | (hi << 16);
            }
            *(u32x4*)(wq + (size_t)l * NPAIR + (lane << 2)) = pk;
        }
    }
}

// ---------------- lateral iteration: 10x10 tile, grid 256 = 1 block/CU ----------------
__global__ __launch_bounds__(BLK, 3) void k_lat(const unsigned* __restrict__ wq,
                                                float* __restrict__ ws,
                                                const float* __restrict__ lsrc,
                                                float* __restrict__ lat_out) {
    __shared__ float Lt[LT_N];
    __shared__ float Ep[EP_N];
    const int b  = blockIdx.x;
    const int i0 = (b / TCOLS) * BH;
    const int j0 = (b % TCOLS) * BW;
    const int tid = threadIdx.x;
    const int w = tid >> 6, lane = tid & 63;
    const int lrow = (i0 + w) * SHEET + j0;        // wave w owns locs lrow+0..9

    // per-lane gather offsets (8 compacted slots)
    const int* offT = (const int*)(ws + WS_OFFT);
    int offr[8];
    #pragma unroll
    for (int q8 = 0; q8 < 8; ++q8) offr[q8] = offT[q8*64 + lane];

    // prefetch all 10 locations' packed weights: one b128 per location
    u32x4 wp[10];
    #pragma unroll
    for (int s = 0; s < 10; ++s)
        wp[s] = *(const u32x4*)(wq + (size_t)(lrow + s) * NPAIR + (lane << 2));
    __builtin_amdgcn_sched_barrier(0);

    // sre (uniform -> scalar loads)
    float sreg[25];
    #pragma unroll
    for (int q = 0; q < 25; ++q) sreg[q] = ws[WS_SRE + q];

    // ---- stage L tile (pad = HOMEO), 62 rows x 62 cols in [62][64] ----
    for (int idx = tid; idx < LT_N; idx += BLK) {
        int r = idx >> 6, c = idx & 63;
        int y  = i0 + r - 26;
        int xx = j0 + c - 26;
        float v = HOMEO;
        if (c < 62 && (unsigned)y < SHEET && (unsigned)xx < SHEET) v = lsrc[y*SHEET + xx];
        Lt[idx] = v;
    }
    __syncthreads();

    // ---- 5x5 conv -> E field 58x58: 6-wide register blocked, SINGLE pass (580<=640) ----
    {
        int qi = tid;
        if (qi < EH * 10) {
            int y = qi / 10, q = qi - y * 10;
            int x0 = q * 6;
            float a0=0.f,a1=0.f,a2=0.f,a3=0.f,a4=0.f,a5=0.f;
            #pragma unroll
            for (int u = 0; u < 5; ++u) {
                const float* row = &Lt[(y + u) * LW + x0];
                float ra[10];
                #pragma unroll
                for (int v = 0; v < 10; ++v) ra[v] = row[v];
                #pragma unroll
                for (int v = 0; v < 5; ++v) {
                    float s = sreg[u * 5 + v];
                    a0 = fmaf(ra[v],     s, a0);
                    a1 = fmaf(ra[v + 1], s, a1);
                    a2 = fmaf(ra[v + 2], s, a2);
                    a3 = fmaf(ra[v + 3], s, a3);
                    a4 = fmaf(ra[v + 4], s, a4);
                    a5 = fmaf(ra[v + 5], s, a5);
                }
            }
            int yg = i0 - 24 + y;
            bool yok = (unsigned)yg < SHEET;
            int xg = j0 - 24 + x0;
            float v0 = (yok && (unsigned)(xg    ) < SHEET) ? a0 : HOMEO;
            float v1 = (yok && (unsigned)(xg + 1) < SHEET) ? a1 : HOMEO;
            float v2 = (yok && (unsigned)(xg + 2) < SHEET) ? a2 : HOMEO;
            float v3 = (yok && (unsigned)(xg + 3) < SHEET) ? a3 : HOMEO;
            float v4 = (yok && (unsigned)(xg + 4) < SHEET) ? a4 : HOMEO;
            float v5 = (yok && (unsigned)(xg + 5) < SHEET) ? a5 : HOMEO;
            // parity split: col x0+k -> half k&1, parity col 3q + (k>>1)
            int c0 = y * EWH + 3 * q;
            Ep[c0]               = v0;
            Ep[c0 + 1]           = v2;
            Ep[c0 + 2]           = v4;   // q=9 -> col 29 = pad slot, never gathered
            Ep[EP_HALF + c0]     = v1;
            Ep[EP_HALF + c0 + 1] = v3;
            Ep[EP_HALF + c0 + 2] = v5;
        }
    }
    __syncthreads();

    // ---- per-location 625-dot from register-resident bf16 weights ----
    float acc[10];
    #pragma unroll
    for (int s = 0; s < 10; ++s) {
        const int gbase = (s & 1) * EP_HALF + w * EWH + (s >> 1);
        float a = 0.f;
        #pragma unroll
        for (int k = 0; k < 4; ++k) {
            unsigned p = wp[s][k];
            float e0 = Ep[gbase + offr[2*k]];
            float e1 = Ep[gbase + offr[2*k + 1]];
            a = fmaf(e0, bflo(p), a);
            a = fmaf(e1, bfhi(p), a);
        }
        acc[s] = a;
    }
    #pragma unroll
    for (int s = 0; s < 10; ++s) acc[s] = wred_dpp(acc[s]);

    // broadcast acc[s] to lane s; lanes 0-9 finish their locations in parallel
    float accs = 0.f;
    #pragma unroll
    for (int s = 0; s < 10; ++s) {
        float a = __int_as_float(__builtin_amdgcn_readlane(__float_as_int(acc[s]), 63));
        if (lane == s) accs = a;
    }
    if (lane < 10) {
        int s = lane;
        int l = lrow + s;
        float ec = Ep[(s & 1) * EP_HALF + (w + 24) * EWH + (s >> 1) + 12];
        float v = ec * 0.45f - accs * 0.55f + ws[WS_AFF + l];
        v = tanhf(fmaxf(v, 0.f));
        lat_out[l] = v;
        ws[WS_LM + l] += v;
    }
}

// ---------------- hebbian correlation: same 10x10 tiling, no conv, atomic sum ----------------
__global__ __launch_bounds__(BLK, 3) void k_hebb(const unsigned* __restrict__ wq,
                                                 float* __restrict__ ws,
                                                 float* __restrict__ out_scalar) {
    __shared__ float LMp[EP_N];
    __shared__ float part[10];
    const int b  = blockIdx.x;
    const int i0 = (b / TCOLS) * BH;
    const int j0 = (b % TCOLS) * BW;
    const int tid = threadIdx.x;
    const int w = tid >> 6, lane = tid & 63;
    const int lrow = (i0 + w) * SHEET + j0;
    const float* lm = ws + WS_LM;

    const int* offT = (const int*)(ws + WS_OFFT);
    int offr[8];
    #pragma unroll
    for (int q8 = 0; q8 < 8; ++q8) offr[q8] = offT[q8*64 + lane];

    u32x4 wp[10];
    #pragma unroll
    for (int s = 0; s < 10; ++s)
        wp[s] = *(const u32x4*)(wq + (size_t)(lrow + s) * NPAIR + (lane << 2));
    __builtin_amdgcn_sched_barrier(0);

    // stage lat_mean tile (x0.1, pad HOMEO), parity-split 58x58
    for (int idx = tid; idx < EP_N; idx += BLK) {
        int p   = idx / EP_HALF;
        int rem = idx - p * EP_HALF;
        int y   = rem / EWH;
        int col = rem - y * EWH;
        int yg = i0 - 24 + y;
        int xg = j0 - 24 + 2 * col + p;
        float v = HOMEO;
        if ((unsigned)yg < SHEET && (unsigned)xg < SHEET && col < 29) v = lm[yg*SHEET + xg] * 0.1f;
        LMp[idx] = v;
    }
    __syncthreads();

    float acc[10];
    #pragma unroll
    for (int s = 0; s < 10; ++s) {
        const int gbase = (s & 1) * EP_HALF + w * EWH + (s >> 1);
        float a = 0.f;
        #pragma unroll
        for (int k = 0; k < 4; ++k) {
            unsigned p = wp[s][k];
            float e0 = LMp[gbase + offr[2*k]];
            float e1 = LMp[gbase + offr[2*k + 1]];
            a = fmaf(e0, bflo(p), a);
            a = fmaf(e1, bfhi(p), a);
        }
        acc[s] = a;
    }
    #pragma unroll
    for (int s = 0; s < 10; ++s) acc[s] = wred_dpp(acc[s]);

    if (lane == 63) {
        float wacc = 0.f;
        #pragma unroll
        for (int s = 0; s < 10; ++s) {
            float lmv = LMp[(s & 1) * EP_HALF + (w + 24) * EWH + (s >> 1) + 12];
            wacc += lmv * 62.5f * acc[s];
        }
        part[w] = wacc;
    }
    __syncthreads();
    if (tid == 0) {
        float s = 0.f;
        #pragma unroll
        for (int q = 0; q < 10; ++q) s += part[q];
        atomicAdd(out_scalar, s);
    }
}

extern "C" void kernel_launch(void* const* d_in, const int* in_sizes, int n_in,
                              void* d_out, int out_size, void* d_ws, size_t ws_size,
                              hipStream_t stream) {
    const float* x    = (const float*)d_in[0];
    const float* rfs  = (const float*)d_in[1];
    const float* latw = (const float*)d_in[2];
    const float* ada  = (const float*)d_in[3];
    float* out = (float*)d_out;
    float* ws  = (float*)d_ws;
    unsigned* wq = (unsigned*)(ws + WS_WQ);

    k_init<<<1, 1024, 0, stream>>>(ws, out);
    k_pre<<<2 * NABLK, PBLK, 0, stream>>>(x, rfs, latw, ada, out, ws, wq);

    for (int t = 0; t < N_ITERS; ++t) {
        const float* src = ws + ((t & 1) ? WS_B1 : WS_B0);
        float* dst = (t == N_ITERS - 1) ? (out + LTOT)
                                        : (ws + ((t & 1) ? WS_B0 : WS_B1));
        k_lat<<<GRID_L, BLK, 0, stream>>>(wq, ws, src, dst);
    }

    k_hebb<<<GRID_L, BLK, 0, stream>>>(wq, ws, out + 2 * LTOT);
}

// Round 18
// 134.194 us; speedup vs baseline: 1.1967x; 1.0087x over previous
//
#include <hip/hip_runtime.h>
#include <math.h>

#define SHEET 160
#define LTOT (SHEET*SHEET)          // 25600
#define F_AFF 450
#define F_LAT 625
#define N_ITERS 10
#define IN_HW 174                   // SHEET + AFF_K - 1
#define HOMEO 0.02f
#define PI_D 3.14159265358979323846

typedef float    f32x4 __attribute__((ext_vector_type(4)));
typedef unsigned u32x4 __attribute__((ext_vector_type(4)));

// ---- lateral tile geometry: 10 x 10 locations per block, 1 block/CU ----
#define BH 10
#define BW 10
#define BLK 1024                    // 16 waves: all stage+conv; waves 0-9 own dot rows
#define TCOLS (SHEET/BW)            // 16
#define GRID_L ((SHEET/BH)*TCOLS)   // 256 blocks = exactly 1/CU
#define EH 58                       // BH + 48 E-field rows
#define EWH 30                      // 29 data cols per parity half + 1 pad
#define EP_HALF (EH*EWH)            // 1740
#define EP_N (2*EP_HALF)            // 3480
#define LW 64                       // 62 data cols padded to 64
#define LH 62                       // BH + 52
#define LT_N (LH*LW)                // 3968

// k_hebb keeps the r14-proven 640-thread shape
#define HBLK 640

// pre-pass geometry: 256-thread blocks, 8 rows each, role-split grid
#define PBLK 256
#define RPB 8
#define NABLK (LTOT/RPB)            // 3200 blocks per role

#define NPAIR 256                   // packed words per location (4 per lane, nz-compacted)

// ---- workspace layout (float offsets) ----
#define WS_SRE    0                 // 32 (25 used)
#define WS_PKF    32                // int[512]   pack-order f index
#define WS_PKL    544               // float[512] pack-order lri
#define WS_OFFT   1056              // int[512]   pack-order gather offset (parity-half stride)
#define WS_AFFTAB 1568              // float2[512] {env, off}
#define WS_AFF    2592
#define WS_B0     (WS_AFF + LTOT)
#define WS_B1     (WS_B0  + LTOT)
#define WS_LM     (WS_B1  + LTOT)
#define WS_WQ     (WS_LM  + LTOT + 64)   // 25600*256 u32 = 26.2 MB

// DPP wave-64 sum: result lands in lane 63 (VALU pipe, no LDS traffic)
__device__ __forceinline__ float wred_dpp(float v) {
    v += __int_as_float(__builtin_amdgcn_update_dpp(0, __float_as_int(v), 0x111, 0xf, 0xf, true)); // row_shr:1
    v += __int_as_float(__builtin_amdgcn_update_dpp(0, __float_as_int(v), 0x112, 0xf, 0xf, true)); // row_shr:2
    v += __int_as_float(__builtin_amdgcn_update_dpp(0, __float_as_int(v), 0x114, 0xf, 0xf, true)); // row_shr:4
    v += __int_as_float(__builtin_amdgcn_update_dpp(0, __float_as_int(v), 0x118, 0xf, 0xf, true)); // row_shr:8
    v += __int_as_float(__builtin_amdgcn_update_dpp(0, __float_as_int(v), 0x142, 0xa, 0xf, true)); // bcast15
    v += __int_as_float(__builtin_amdgcn_update_dpp(0, __float_as_int(v), 0x143, 0xc, 0xf, true)); // bcast31
    return v;
}

__device__ __forceinline__ unsigned f2bf(float f) {   // RNE float->bf16 bits
    unsigned u = __float_as_uint(f);
    return (u + 0x7FFFu + ((u >> 16) & 1u)) >> 16;
}
__device__ __forceinline__ float bflo(unsigned p) { return __uint_as_float(p << 16); }
__device__ __forceinline__ float bfhi(unsigned p) { return __uint_as_float(p & 0xffff0000u); }

// ---------------- init: constant tables + nz-compacted pack tables + scalar zero ----------------
__global__ __launch_bounds__(1024) void k_init(float* __restrict__ ws,
                                               float* __restrict__ out) {
    __shared__ float red[1024];
    __shared__ float lriS[640];
    __shared__ int   nzf[512];
    __shared__ int   wcnt[16];
    const int t = threadIdx.x;
    const int lane = t & 63, wvi = t >> 6;

    if (t == 0) out[2 * LTOT] = 0.f;   // k_hebb atomicAdds into this

    float sre_raw = 0.f;
    if (t < 25) {
        int u = t / 5, v = t % 5;
        double d = sqrt((double)((u-2)*(u-2) + (v-2)*(v-2)));
        if (d < 2.5) { double cv = cos(fmin(d/5.0, 1.0) * PI_D * 0.5); sre_raw = (float)(cv*cv); }
    }

    float lri_raw = 0.f;
    const int dy = t / 25, dx = t % 25;
    if (t < 625) {
        double d = sqrt((double)((dy-12)*(dy-12) + (dx-12)*(dx-12)));
        double base = 0.0, inh = 0.0;
        if (d < 12.5) { double cv = cos(fmin(d/25.0, 1.0) * PI_D * 0.5); base = cv*cv; }
        if (d < 1.25) { double cv = cos(fmin(d/2.5,  1.0) * PI_D * 0.5); inh  = cv*cv; }
        lri_raw = (float)(base * (1.0 - inh));
    }
    const bool nz = (lri_raw != 0.f);
    if (t < 640) lriS[t] = lri_raw;

    red[t] = lri_raw;
    __syncthreads();
    #pragma unroll
    for (int s = 512; s > 0; s >>= 1) {
        if (t < s) red[t] = fmaxf(red[t], red[t + s]);
        __syncthreads();
    }
    const float lri_max = red[0];
    __syncthreads();

    red[t] = sre_raw;
    __syncthreads();
    #pragma unroll
    for (int s = 512; s > 0; s >>= 1) {
        if (t < s) red[t] += red[t + s];
        __syncthreads();
    }
    const float sre_sum = red[0];

    if (t < 32) ws[WS_SRE + t] = (t < 25) ? sre_raw / sre_sum : 0.f;

    // ---- ballot prefix-scan -> compacted nonzero-lri list (488 entries) ----
    unsigned long long bal = __ballot(nz);
    if (lane == 0) wcnt[wvi] = __popcll(bal);
    __syncthreads();
    int woff = 0, ntot = 0;
    #pragma unroll
    for (int v2 = 0; v2 < 16; ++v2) { int c = wcnt[v2]; if (v2 < wvi) woff += c; ntot += c; }
    if (nz) nzf[woff + __popcll(bal & ((1ull << lane) - 1ull))] = t;
    __syncthreads();

    // pack tables: slot (2q+h)*64+lane <- nzf[2*(q*64+lane)+h]
    if (t < 256) {
        #pragma unroll
        for (int h = 0; h < 2; ++h) {
            int idx = 2*t + h;
            int f = 624, off = 0; float lv = 0.f;
            if (idx < ntot) {
                f = nzf[idx];
                int fy = f / 25, fx = f - 25*fy;
                off = fy * (2*EWH) + fx;
                lv = lriS[f] / lri_max;
            }
            int slot = (2*(t >> 6) + h)*64 + (t & 63);
            ((int*)  (ws + WS_PKF ))[slot] = f;
            ((float*)(ws + WS_PKL ))[slot] = lv;
            ((int*)  (ws + WS_OFFT))[slot] = off;
        }
    }

    // afferent table: {env, x offset}
    if (t < 512) {
        float ev = 0.f; int off = 0;
        if (t < 450) {
            int c  = t / 225, rr = t % 225;
            int kh = rr / 15, kw = rr % 15;
            double d = sqrt((double)((kh-7)*(kh-7) + (kw-7)*(kw-7)));
            if (d < 7.5) { double cv = cos(fmin(d/15.0, 1.0) * PI_D * 0.5); ev = (float)(cv*cv); }
            off = c * (IN_HW*IN_HW) + kh * IN_HW + kw;
        }
        ((float2*)(ws + WS_AFFTAB))[t] = make_float2(ev, __int_as_float(off));
    }
}

// ---------------- pre-pass: float4-staged streaming, 20KB LDS -> 8 blocks/CU ----------------
// blocks [0, NABLK): afferent (rfs).  blocks [NABLK, 2*NABLK): latw pack.
__global__ __launch_bounds__(PBLK, 8) void k_pre(const float* __restrict__ x,
                                                 const float* __restrict__ rfs,
                                                 const float* __restrict__ latw,
                                                 const float* __restrict__ ada,
                                                 float* __restrict__ out_rawaff,
                                                 float* __restrict__ ws,
                                                 unsigned* __restrict__ wq) {
    __shared__ __align__(16) float S[5008];    // 20 KB: pack 5000, aff 3600
    const int tid = threadIdx.x;
    const int w = tid >> 6, lane = tid & 63;

    if (blockIdx.x < NABLK) {
        // ---- afferent role: stage 8 rows of rfs (900 float4, 4 indep loads/thread) ----
        const int l0 = blockIdx.x * RPB;
        const f32x4* src4 = (const f32x4*)(rfs + (size_t)l0 * F_AFF);
        #pragma unroll
        for (int k = 0; k < 4; ++k) {
            int idx = k * PBLK + tid;
            if (idx < 900) ((f32x4*)S)[idx] = __builtin_nontemporal_load(src4 + idx);
        }

        // hoist afferent table into regs (shared across the wave's 2 rows)
        float envA[8]; int offA[8];
        const float2* atab = (const float2*)(ws + WS_AFFTAB);
        #pragma unroll
        for (int it = 0; it < 8; ++it) {
            float2 tb = atab[it*64 + lane];
            envA[it] = tb.x; offA[it] = __float_as_int(tb.y);
        }
        __syncthreads();

        #pragma unroll
        for (int s = 0; s < 2; ++s) {
            const int row = 2*w + s, l = l0 + row;
            const int i = l / SHEET, j = l % SHEET;
            const int xbase = i * IN_HW + j;
            const float* Srow = S + row * F_AFF;
            float dot = 0.f, rs = 0.f;
            #pragma unroll
            for (int it = 0; it < 8; ++it) {
                int f = it*64 + lane;
                float r = (f < F_AFF) ? Srow[f] : 0.f;
                float xv = x[xbase + offA[it]];
                dot = fmaf(xv * envA[it], r, dot);
                rs += r;
            }
            dot = wred_dpp(dot); rs = wred_dpp(rs);
            if (lane == 63) {
                float a = dot / rs;
                out_rawaff[l] = 45.0f * a;             // raw_aff
                float aff = a - ada[l];
                ws[WS_AFF + l] = aff;
                ws[WS_B0  + l] = fmaxf(aff, 0.f);      // lat_0 = relu(aff)
                ws[WS_LM  + l] = 0.f;
            }
        }
    } else {
        // ---- pack role: stage 8 rows of latw (1250 float4, 5 indep loads/thread) ----
        const int l0 = (blockIdx.x - NABLK) * RPB;
        const f32x4* src4 = (const f32x4*)(latw + (size_t)l0 * F_LAT);
        #pragma unroll
        for (int k = 0; k < 5; ++k) {
            int idx = k * PBLK + tid;
            if (idx < 1250) ((f32x4*)S)[idx] = __builtin_nontemporal_load(src4 + idx);
        }

        // hoist pack tables into regs
        int pf[8]; float pl[8];
        #pragma unroll
        for (int q8 = 0; q8 < 8; ++q8) {
            pf[q8] = ((const int*)  (ws + WS_PKF))[q8*64 + lane];
            pl[q8] = ((const float*)(ws + WS_PKL))[q8*64 + lane];
        }
        __syncthreads();

        #pragma unroll
        for (int s = 0; s < 2; ++s) {
            const int row = 2*w + s, l = l0 + row;
            const float* Srow = S + row * F_LAT;
            float sum = 0.f;
            #pragma unroll
            for (int it = 0; it < 10; ++it) {
                int f = it*64 + lane;
                sum += (f < F_LAT) ? Srow[f] : 0.f;
            }
            sum = wred_dpp(sum);
            const float inv = 1.0f / __int_as_float(__builtin_amdgcn_readlane(__float_as_int(sum), 63));
            // per-lane-contiguous layout: one coalesced 16B store per lane
            u32x4 pk;
            #pragma unroll
            for (int q = 0; q < 4; ++q) {
                unsigned lo = f2bf(Srow[pf[2*q]]     * pl[2*q]     * inv);
                unsigned hi = f2bf(Srow[pf[2*q + 1]] * pl[2*q + 1] * inv);
                pk[q] = lo | (hi << 16);
            }
            *(u32x4*)(wq + (size_t)l * NPAIR + (lane << 2)) = pk;
        }
    }
}

// ---------------- lateral iteration: 10x10 tile, 16 waves (4/SIMD latency hiding) ----------------
__global__ __launch_bounds__(BLK, 2) void k_lat(const unsigned* __restrict__ wq,
                                                float* __restrict__ ws,
                                                const float* __restrict__ lsrc,
                                                float* __restrict__ lat_out) {
    __shared__ float Lt[LT_N];
    __shared__ float Ep[EP_N];
    const int b  = blockIdx.x;
    const int i0 = (b / TCOLS) * BH;
    const int j0 = (b % TCOLS) * BW;
    const int tid = threadIdx.x;
    const int w = tid >> 6, lane = tid & 63;
    const bool dotwave = (w < 10);
    const int lrow = dotwave ? ((i0 + w) * SHEET + j0) : 0;   // wave w<10 owns locs lrow+0..9

    // sre (uniform -> scalar loads), needed by all waves for conv
    float sreg[25];
    #pragma unroll
    for (int q = 0; q < 25; ++q) sreg[q] = ws[WS_SRE + q];

    // per-lane gather offsets + weight prefetch: dot waves only
    int offr[8];
    u32x4 wp[10];
    if (dotwave) {
        const int* offT = (const int*)(ws + WS_OFFT);
        #pragma unroll
        for (int q8 = 0; q8 < 8; ++q8) offr[q8] = offT[q8*64 + lane];
        #pragma unroll
        for (int s = 0; s < 10; ++s)
            wp[s] = *(const u32x4*)(wq + (size_t)(lrow + s) * NPAIR + (lane << 2));
    }
    __builtin_amdgcn_sched_barrier(0);

    // ---- stage L tile (pad = HOMEO), 62 rows x 62 cols in [62][64], all 16 waves ----
    for (int idx = tid; idx < LT_N; idx += BLK) {
        int r = idx >> 6, c = idx & 63;
        int y  = i0 + r - 26;
        int xx = j0 + c - 26;
        float v = HOMEO;
        if (c < 62 && (unsigned)y < SHEET && (unsigned)xx < SHEET) v = lsrc[y*SHEET + xx];
        Lt[idx] = v;
    }
    __syncthreads();

    // ---- 5x5 conv -> E field 58x58: 6-wide register blocked, single pass (580<=1024) ----
    if (tid < EH * 10) {
        int y = tid / 10, q = tid - y * 10;
        int x0 = q * 6;
        float a0=0.f,a1=0.f,a2=0.f,a3=0.f,a4=0.f,a5=0.f;
        #pragma unroll
        for (int u = 0; u < 5; ++u) {
            const float* row = &Lt[(y + u) * LW + x0];
            float ra[10];
            #pragma unroll
            for (int v = 0; v < 10; ++v) ra[v] = row[v];
            #pragma unroll
            for (int v = 0; v < 5; ++v) {
                float s = sreg[u * 5 + v];
                a0 = fmaf(ra[v],     s, a0);
                a1 = fmaf(ra[v + 1], s, a1);
                a2 = fmaf(ra[v + 2], s, a2);
                a3 = fmaf(ra[v + 3], s, a3);
                a4 = fmaf(ra[v + 4], s, a4);
                a5 = fmaf(ra[v + 5], s, a5);
            }
        }
        int yg = i0 - 24 + y;
        bool yok = (unsigned)yg < SHEET;
        int xg = j0 - 24 + x0;
        float v0 = (yok && (unsigned)(xg    ) < SHEET) ? a0 : HOMEO;
        float v1 = (yok && (unsigned)(xg + 1) < SHEET) ? a1 : HOMEO;
        float v2 = (yok && (unsigned)(xg + 2) < SHEET) ? a2 : HOMEO;
        float v3 = (yok && (unsigned)(xg + 3) < SHEET) ? a3 : HOMEO;
        float v4 = (yok && (unsigned)(xg + 4) < SHEET) ? a4 : HOMEO;
        float v5 = (yok && (unsigned)(xg + 5) < SHEET) ? a5 : HOMEO;
        // parity split: col x0+k -> half k&1, parity col 3q + (k>>1)
        int c0 = y * EWH + 3 * q;
        Ep[c0]               = v0;
        Ep[c0 + 1]           = v2;
        Ep[c0 + 2]           = v4;   // q=9 -> col 29 = pad slot, never gathered
        Ep[EP_HALF + c0]     = v1;
        Ep[EP_HALF + c0 + 1] = v3;
        Ep[EP_HALF + c0 + 2] = v5;
    }
    __syncthreads();

    // ---- per-location 625-dot from register-resident bf16 weights (waves 0-9) ----
    if (dotwave) {
        float acc[10];
        #pragma unroll
        for (int s = 0; s < 10; ++s) {
            const int gbase = (s & 1) * EP_HALF + w * EWH + (s >> 1);
            float a = 0.f;
            #pragma unroll
            for (int k = 0; k < 4; ++k) {
                unsigned p = wp[s][k];
                float e0 = Ep[gbase + offr[2*k]];
                float e1 = Ep[gbase + offr[2*k + 1]];
                a = fmaf(e0, bflo(p), a);
                a = fmaf(e1, bfhi(p), a);
            }
            acc[s] = a;
        }
        #pragma unroll
        for (int s = 0; s < 10; ++s) acc[s] = wred_dpp(acc[s]);

        // broadcast acc[s] to lane s; lanes 0-9 finish their locations in parallel
        float accs = 0.f;
        #pragma unroll
        for (int s = 0; s < 10; ++s) {
            float a = __int_as_float(__builtin_amdgcn_readlane(__float_as_int(acc[s]), 63));
            if (lane == s) accs = a;
        }
        if (lane < 10) {
            int s = lane;
            int l = lrow + s;
            float ec = Ep[(s & 1) * EP_HALF + (w + 24) * EWH + (s >> 1) + 12];
            float v = ec * 0.45f - accs * 0.55f + ws[WS_AFF + l];
            v = tanhf(fmaxf(v, 0.f));
            lat_out[l] = v;
            ws[WS_LM + l] += v;
        }
    }
}

// ---------------- hebbian correlation: 10x10 tiling, 640 threads, atomic sum ----------------
__global__ __launch_bounds__(HBLK, 3) void k_hebb(const unsigned* __restrict__ wq,
                                                  float* __restrict__ ws,
                                                  float* __restrict__ out_scalar) {
    __shared__ float LMp[EP_N];
    __shared__ float part[10];
    const int b  = blockIdx.x;
    const int i0 = (b / TCOLS) * BH;
    const int j0 = (b % TCOLS) * BW;
    const int tid = threadIdx.x;
    const int w = tid >> 6, lane = tid & 63;
    const int lrow = (i0 + w) * SHEET + j0;
    const float* lm = ws + WS_LM;

    const int* offT = (const int*)(ws + WS_OFFT);
    int offr[8];
    #pragma unroll
    for (int q8 = 0; q8 < 8; ++q8) offr[q8] = offT[q8*64 + lane];

    u32x4 wp[10];
    #pragma unroll
    for (int s = 0; s < 10; ++s)
        wp[s] = *(const u32x4*)(wq + (size_t)(lrow + s) * NPAIR + (lane << 2));
    __builtin_amdgcn_sched_barrier(0);

    // stage lat_mean tile (x0.1, pad HOMEO), parity-split 58x58
    for (int idx = tid; idx < EP_N; idx += HBLK) {
        int p   = idx / EP_HALF;
        int rem = idx - p * EP_HALF;
        int y   = rem / EWH;
        int col = rem - y * EWH;
        int yg = i0 - 24 + y;
        int xg = j0 - 24 + 2 * col + p;
        float v = HOMEO;
        if ((unsigned)yg < SHEET && (unsigned)xg < SHEET && col < 29) v = lm[yg*SHEET + xg] * 0.1f;
        LMp[idx] = v;
    }
    __syncthreads();

    float acc[10];
    #pragma unroll
    for (int s = 0; s < 10; ++s) {
        const int gbase = (s & 1) * EP_HALF + w * EWH + (s >> 1);
        float a = 0.f;
        #pragma unroll
        for (int k = 0; k < 4; ++k) {
            unsigned p = wp[s][k];
            float e0 = LMp[gbase + offr[2*k]];
            float e1 = LMp[gbase + offr[2*k + 1]];
            a = fmaf(e0, bflo(p), a);
            a = fmaf(e1, bfhi(p), a);
        }
        acc[s] = a;
    }
    #pragma unroll
    for (int s = 0; s < 10; ++s) acc[s] = wred_dpp(acc[s]);

    if (lane == 63) {
        float wacc = 0.f;
        #pragma unroll
        for (int s = 0; s < 10; ++s) {
            float lmv = LMp[(s & 1) * EP_HALF + (w + 24) * EWH + (s >> 1) + 12];
            wacc += lmv * 62.5f * acc[s];
        }
        part[w] = wacc;
    }
    __syncthreads();
    if (tid == 0) {
        float s = 0.f;
        #pragma unroll
        for (int q = 0; q < 10; ++q) s += part[q];
        atomicAdd(out_scalar, s);
    }
}

extern "C" void kernel_launch(void* const* d_in, const int* in_sizes, int n_in,
                              void* d_out, int out_size, void* d_ws, size_t ws_size,
                              hipStream_t stream) {
    const float* x    = (const float*)d_in[0];
    const float* rfs  = (const float*)d_in[1];
    const float* latw = (const float*)d_in[2];
    const float* ada  = (const float*)d_in[3];
    float* out = (float*)d_out;
    float* ws  = (float*)d_ws;
    unsigned* wq = (unsigned*)(ws + WS_WQ);

    k_init<<<1, 1024, 0, stream>>>(ws, out);
    k_pre<<<2 * NABLK, PBLK, 0, stream>>>(x, rfs, latw, ada, out, ws, wq);

    for (int t = 0; t < N_ITERS; ++t) {
        const float* src = ws + ((t & 1) ? WS_B1 : WS_B0);
        float* dst = (t == N_ITERS - 1) ? (out + LTOT)
                                        : (ws + ((t & 1) ? WS_B0 : WS_B1));
        k_lat<<<GRID_L, BLK, 0, stream>>>(wq, ws, src, dst);
    }

    k_hebb<<<GRID_L, HBLK, 0, stream>>>(wq, ws, out + 2 * LTOT);
}